// Round 14
// baseline (10862.006 us; speedup 1.0000x reference)
//
#include <hip/hip_runtime.h>
#include <math.h>

namespace {

constexpr int BB = 4;
constexpr int N0 = 16384;
constexpr int S1 = 2048;
constexpr int S2 = 1024;

// ---- exact f32 helpers (no contraction) ----
__device__ __forceinline__ float sq3(float x, float y, float z){
  #pragma clang fp contract(off)
  return x*x + y*y + z*z;
}
__device__ __forceinline__ float sqdist(float ax,float ay,float az,float bx,float by,float bz){
  #pragma clang fp contract(off)
  float dx = ax-bx; float dy = ay-by; float dz = az-bz;
  return dx*dx + dy*dy + dz*dz;
}
__device__ __forceinline__ float dot3(float ax,float ay,float az,float bx,float by,float bz){
  #pragma clang fp contract(off)
  return ax*bx + ay*by + az*bz;
}
__device__ __forceinline__ float knndist(float qs, float dot, float rs){
  #pragma clang fp contract(off)
  return (qs - 2.0f*dot) + rs;
}

// ---------------- setup: raw f32, point-major layout ----------------
__global__ __launch_bounds__(256) void k_setup(const float* __restrict__ pc,
                                               const float* __restrict__ feat,
                                               float* __restrict__ out_pc,
                                               float* __restrict__ xyz,
                                               float* __restrict__ fN,
                                               float* __restrict__ rsq0)
{
  int t = blockIdx.x*256 + threadIdx.x;
  if (t < BB*3*N0) out_pc[t] = pc[t];
  if (t < BB*N0){
    int b = t >> 14, n = t & (N0-1);
    const float* p = pc + (size_t)b*3*N0;
    float x = p[n], y = p[N0+n], z = p[2*N0+n];
    float* q = xyz + (size_t)t*3;
    q[0]=x; q[1]=y; q[2]=z;
    rsq0[t] = sq3(x,y,z);
    const float* f = feat + (size_t)b*3*N0;
    float* g = fN + (size_t)t*3;
    g[0]=f[n]; g[1]=f[N0+n]; g[2]=f[2*N0+n];
  }
}

// ---------------- FPS: Euclidean-norm (sqrt) distances, first-index ties ----------------
__device__ __forceinline__ void red2(float& v, int& i){
  #pragma unroll
  for (int off=32; off>0; off>>=1){
    float ov = __shfl_down(v, off);
    int   oi = __shfl_down(i, off);
    if (ov > v || (ov == v && oi < i)){ v = ov; i = oi; }   // tie -> lowest index
  }
}

__device__ __forceinline__ void fps_writeout(int b, int i, float cx, float cy, float cz, int far,
                                             float* sxyz, float* srsq, float* pcl, float* fidxf, int NP)
{
  fidxf[(size_t)b*NP + i] = (float)far;
  float* o = sxyz + ((size_t)b*NP + i)*3;
  o[0]=cx; o[1]=cy; o[2]=cz;
  float* pb = pcl + (size_t)b*3*NP;
  pb[i] = cx; pb[NP+i] = cy; pb[2*NP+i] = cz;
  srsq[(size_t)b*NP + i] = sq3(cx,cy,cz);
}

template<int N, int NP, int BS, int PPT>
__global__ __launch_bounds__(BS) void k_fps(const float* __restrict__ pts,   // [B][N][3]
                                            float* __restrict__ sxyz,        // [B][NP][3]
                                            float* __restrict__ srsq,        // [B][NP]
                                            float* __restrict__ pcl,         // [B][3][NP]
                                            float* __restrict__ fidxf)       // [B][NP] (float)
{
  static_assert(N == BS*PPT, "bad fps shape");
  constexpr int NW = BS/64;
  int b = blockIdx.x, t = threadIdx.x;
  const float* P = pts + (size_t)b*N*3;
  float px[PPT], py[PPT], pz[PPT], dist[PPT];
  #pragma unroll
  for (int j=0;j<PPT;j++){
    int g = t + BS*j;
    px[j]=P[g*3]; py[j]=P[g*3+1]; pz[j]=P[g*3+2];
    dist[j]=1e10f;
  }
  __shared__ float s_c[3];
  __shared__ float s_wv[16];
  __shared__ int   s_wi[16];
  if (t == 0){
    float cx=P[0], cy=P[1], cz=P[2];
    s_c[0]=cx; s_c[1]=cy; s_c[2]=cz;
    fps_writeout(b, 0, cx, cy, cz, 0, sxyz, srsq, pcl, fidxf, NP);
  }
  __syncthreads();
  for (int i=1;i<NP;i++){
    float cx=s_c[0], cy=s_c[1], cz=s_c[2];
    float bv = -1.0f; int bi = 0;
    #pragma unroll
    for (int j=0;j<PPT;j++){
      float d  = sqrtf(sqdist(px[j],py[j],pz[j],cx,cy,cz));   // Euclidean norm (IEEE sqrt)
      float nd = fminf(dist[j], d);
      dist[j]  = nd;
      if (nd > bv){ bv = nd; bi = t + BS*j; }   // strict >: first-max within thread
    }
    red2(bv, bi);
    if ((t & 63) == 0){ s_wv[t>>6]=bv; s_wi[t>>6]=bi; }
    __syncthreads();
    if (t < 64){
      float v = (t < NW) ? s_wv[t] : -1.0f;
      int  ii = (t < NW) ? s_wi[t] : 0x7FFFFFFF;
      red2(v, ii);
      if (t == 0){
        int far = ii;
        float cx2=P[(size_t)far*3], cy2=P[(size_t)far*3+1], cz2=P[(size_t)far*3+2];
        s_c[0]=cx2; s_c[1]=cy2; s_c[2]=cz2;
        fps_writeout(b, i, cx2, cy2, cz2, far, sxyz, srsq, pcl, fidxf, NP);
      }
    }
    __syncthreads();
  }
}

// ---------------- exact kNN (32 smallest) via radix select ----------------
template<int NREF, int PPT, int NQ>
__global__ __launch_bounds__(512) void k_knn(const float* __restrict__ qxyz,
                                             const float* __restrict__ qrsq,
                                             const float* __restrict__ rxyz,
                                             const float* __restrict__ rrsq,
                                             int* __restrict__ nidx)
{
  static_assert(NREF == 512*PPT, "bad knn shape");
  int q = blockIdx.x;
  int b = q / NQ;
  int t = threadIdx.x;
  const float* R  = rxyz + (size_t)b*NREF*3;
  const float* RS = rrsq + (size_t)b*NREF;
  float qx = qxyz[(size_t)q*3], qy = qxyz[(size_t)q*3+1], qz = qxyz[(size_t)q*3+2];
  float qs = qrsq[q];
  unsigned u[PPT];
  #pragma unroll
  for (int j=0;j<PPT;j++){
    int g = t + 512*j;
    float rx=R[g*3], ry=R[g*3+1], rz=R[g*3+2];
    float d = knndist(qs, dot3(qx,qy,qz,rx,ry,rz), RS[g]);
    unsigned bu = __float_as_uint(d);
    u[j] = ((int)bu < 0) ? ~bu : (bu | 0x80000000u);
  }
  __shared__ unsigned hist[256];
  __shared__ unsigned s_pref, s_pm, s_want, s_cnteq;
  __shared__ int s_n;
  __shared__ int s_eq[1024];
  __shared__ int s_ne;
  if (t == 0){ s_pref=0u; s_pm=0u; s_want=32u; s_n=0; s_ne=0; }

  for (int shift=24; shift>=0; shift-=8){
    if (t < 256) hist[t] = 0u;
    __syncthreads();
    unsigned pref = s_pref, pm = s_pm;
    #pragma unroll
    for (int j=0;j<PPT;j++){
      if ((u[j] & pm) == pref) atomicAdd(&hist[(u[j]>>shift)&255], 1u);
    }
    __syncthreads();
    if (t < 64){
      unsigned h0=hist[4*t], h1=hist[4*t+1], h2=hist[4*t+2], h3=hist[4*t+3];
      unsigned ssum = h0+h1+h2+h3;
      unsigned inc = ssum;
      #pragma unroll
      for (int off=1; off<64; off<<=1){
        unsigned o = __shfl_up(inc, off);
        if (t >= off) inc += o;
      }
      unsigned exc = inc - ssum;
      unsigned want = s_want;
      if (exc < want && want <= inc){
        unsigned rem = want - exc;
        unsigned bin, below;
        if      (rem <= h0)       { bin=4*t+0; below=exc; }
        else if (rem <= h0+h1)    { bin=4*t+1; below=exc+h0; }
        else if (rem <= h0+h1+h2) { bin=4*t+2; below=exc+h0+h1; }
        else                      { bin=4*t+3; below=exc+h0+h1+h2; }
        s_pref = pref | (bin << shift);
        s_pm   = pm   | (0xFFu << shift);
        s_want = want - below;
        if (shift == 0) s_cnteq = hist[bin];
      }
    }
    __syncthreads();
  }
  unsigned T = s_pref;
  unsigned krem = s_want;
  unsigned cnteq = s_cnteq;
  int* outq = nidx + (size_t)q*32;
  #pragma unroll
  for (int j=0;j<PPT;j++){
    if (u[j] < T){ int p = atomicAdd(&s_n, 1); outq[p] = t + 512*j; }
  }
  __syncthreads();
  if (cnteq == krem){
    #pragma unroll
    for (int j=0;j<PPT;j++){
      if (u[j] == T){ int p = atomicAdd(&s_n, 1); outq[p] = t + 512*j; }
    }
  } else {
    #pragma unroll
    for (int j=0;j<PPT;j++){
      if (u[j] == T){ int p = atomicAdd(&s_ne, 1); if (p < 1024) s_eq[p] = t + 512*j; }
    }
    __syncthreads();
    if (t == 0){
      int ne = s_ne; if (ne > 1024) ne = 1024;
      int p = s_n;
      int take = (int)krem; if (take > ne) take = ne;
      for (int r=0; r<take; r++){
        int mn = 0x7FFFFFFF, mi = -1;
        for (int e=0; e<ne; e++){ if (s_eq[e] < mn){ mn = s_eq[e]; mi = e; } }
        if (mi < 0) break;
        outq[p++] = mn;
        s_eq[mi] = 0x7FFFFFFF;
      }
    }
  }
}

// ---------------- per-layer sum/sumsq accumulation ----------------
template<int C>
__device__ __forceinline__ void accum_sums(const float* o, int b, float* sums){
  __shared__ float s_sum[C];
  __shared__ float s_ssq[C];
  int t = threadIdx.x;
  if (t < C){ s_sum[t]=0.f; s_ssq[t]=0.f; }
  __syncthreads();
  int lane = t & 63;
  #pragma unroll
  for (int c=0;c<C;c++){
    float v = o[c], v2 = v*v;
    #pragma unroll
    for (int off=32; off>0; off>>=1){ v += __shfl_down(v, off); v2 += __shfl_down(v2, off); }
    if (lane == 0){ atomicAdd(&s_sum[c], v); atomicAdd(&s_ssq[c], v2); }
  }
  __syncthreads();
  if (t < C){
    atomicAdd(&sums[(b*64+t)*2],   s_sum[t]);
    atomicAdd(&sums[(b*64+t)*2+1], s_ssq[t]);
  }
}

// ---------------- SA1 layer 1 ----------------
__global__ __launch_bounds__(256) void k_sa1_l1(const float* __restrict__ xyz,
                                                const float* __restrict__ fN,
                                                const float* __restrict__ sxyz,
                                                const int* __restrict__ nidx,
                                                const float* __restrict__ W,
                                                float* __restrict__ xout,
                                                float* __restrict__ sums)
{
  __shared__ float sW[192];
  int t = threadIdx.x;
  if (t < 192) sW[t] = W[t];
  int row = blockIdx.x*256 + t;
  int b = row >> 16;
  int sk = row & 65535;
  int s = sk >> 5;
  int nb = nidx[row];
  const float* pr = xyz  + ((size_t)(b*N0 + nb))*3;
  const float* pq = sxyz + ((size_t)(b*S1 + s ))*3;
  const float* pf = fN   + ((size_t)(b*N0 + nb))*3;
  float i0 = pr[0]-pq[0], i1 = pr[1]-pq[1], i2 = pr[2]-pq[2];
  float i3 = pf[0], i4 = pf[1], i5 = pf[2];
  __syncthreads();
  float o[32];
  #pragma unroll
  for (int c=0;c<32;c++){
    float a = i0*sW[c];
    a = fmaf(i1, sW[ 32+c], a);
    a = fmaf(i2, sW[ 64+c], a);
    a = fmaf(i3, sW[ 96+c], a);
    a = fmaf(i4, sW[128+c], a);
    a = fmaf(i5, sW[160+c], a);
    o[c] = a;
    xout[(size_t)c*262144 + row] = a;
  }
  accum_sums<32>(o, b, sums);
}

// ---------------- mid layer ----------------
template<int CIN, int COUT, int LRPB>
__global__ __launch_bounds__(256) void k_sa_mid(const float* __restrict__ xin,
                                                const float* __restrict__ W,
                                                const float* __restrict__ sums_in,
                                                float* __restrict__ xout,
                                                float* __restrict__ sums_out,
                                                int rows_total, float invM)
{
  __shared__ float sW[CIN*COUT];
  __shared__ float s_mu[CIN];
  __shared__ float s_rs[CIN];
  int t = threadIdx.x;
  int row = blockIdx.x*256 + t;
  int bb = (blockIdx.x*256) >> LRPB;
  for (int i=t; i<CIN*COUT; i+=256) sW[i] = W[i];
  if (t < CIN){
    float sm = sums_in[(bb*64+t)*2], sq = sums_in[(bb*64+t)*2+1];
    float mu = sm*invM;
    float var = fmaxf(sq*invM - mu*mu, 0.f);
    s_mu[t] = mu;
    s_rs[t] = 1.0f/sqrtf(var + 1e-5f);
  }
  __syncthreads();
  float o[COUT];
  #pragma unroll
  for (int d=0;d<COUT;d++) o[d] = 0.f;
  #pragma unroll
  for (int c=0;c<CIN;c++){
    float x = xin[(size_t)c*rows_total + row];
    float v = fmaxf((x - s_mu[c])*s_rs[c], 0.f);
    #pragma unroll
    for (int d=0;d<COUT;d++) o[d] = fmaf(v, sW[c*COUT+d], o[d]);
  }
  #pragma unroll
  for (int d=0;d<COUT;d++) xout[(size_t)d*rows_total + row] = o[d];
  accum_sums<COUT>(o, bb, sums_out);
}

// ---------------- SA2 layer 1 ----------------
__global__ __launch_bounds__(256) void k_sa2_l1(const float* __restrict__ xyz1,
                                                const float* __restrict__ feat1,
                                                const float* __restrict__ xyz2,
                                                const int* __restrict__ nidx,
                                                const float* __restrict__ W,
                                                float* __restrict__ xout,
                                                float* __restrict__ sums)
{
  __shared__ float sW[35*64];
  int t = threadIdx.x;
  for (int i=t; i<35*64; i+=256) sW[i] = W[i];
  int row = blockIdx.x*256 + t;
  int b = row >> 15;
  int sk = row & 32767;
  int s = sk >> 5;
  int nb = nidx[row];
  const float* pr = xyz1 + ((size_t)(b*S1 + nb))*3;
  const float* pq = xyz2 + ((size_t)(b*S2 + s ))*3;
  const float* pf = feat1 + ((size_t)(b*S1 + nb))*32;
  float i0 = pr[0]-pq[0], i1 = pr[1]-pq[1], i2 = pr[2]-pq[2];
  float fv[32];
  #pragma unroll
  for (int c=0;c<32;c++) fv[c] = pf[c];
  __syncthreads();
  float o[64];
  #pragma unroll
  for (int d=0;d<64;d++){
    float a = i0*sW[d];
    a = fmaf(i1, sW[ 64+d], a);
    a = fmaf(i2, sW[128+d], a);
    o[d] = a;
  }
  #pragma unroll
  for (int c=0;c<32;c++){
    float v = fv[c];
    #pragma unroll
    for (int d=0;d<64;d++) o[d] = fmaf(v, sW[(3+c)*64+d], o[d]);
  }
  #pragma unroll
  for (int d=0;d<64;d++) xout[(size_t)d*131072 + row] = o[d];
  accum_sums<64>(o, b, sums);
}

// ---------------- final norm+relu+maxpool ----------------
template<int C, int PTSB, int CF>
__global__ __launch_bounds__(256) void k_pool(const float* __restrict__ xin,
                                              const float* __restrict__ sums_in,
                                              float* __restrict__ out,
                                              int rows_total, float invM)
{
  int t = threadIdx.x;
  int c = t & (C-1);
  int pl = t / C;
  int p = blockIdx.x*(256/C) + pl;
  int b = p / PTSB;
  float sm = sums_in[(b*64+c)*2], sq = sums_in[(b*64+c)*2+1];
  float mu = sm*invM;
  float var = fmaxf(sq*invM - mu*mu, 0.f);
  float rs = 1.0f/sqrtf(var + 1e-5f);
  const float* xp = xin + (size_t)c*rows_total + (size_t)p*32;
  float m = -1e30f;
  #pragma unroll
  for (int k=0;k<32;k++) m = fmaxf(m, xp[k]);
  m = fmaxf((m - mu)*rs, 0.0f);
  if (CF) out[((size_t)(b*C + c))*PTSB + (p - b*PTSB)] = m;
  else    out[(size_t)p*C + c] = m;
}

// ---------------- workspace layout (float element offsets) ----------------
constexpr size_t WS_XYZ   = 0;
constexpr size_t WS_FN    = WS_XYZ   + 196608;
constexpr size_t WS_RSQ0  = WS_FN    + 196608;
constexpr size_t WS_XYZ1  = WS_RSQ0  + 65536;
constexpr size_t WS_RSQ1  = WS_XYZ1  + 24576;
constexpr size_t WS_XYZ2  = WS_RSQ1  + 8192;
constexpr size_t WS_RSQ2  = WS_XYZ2  + 12288;
constexpr size_t WS_FEAT1 = WS_RSQ2  + 4096;
constexpr size_t WS_SUMS  = WS_FEAT1 + 262144;
constexpr size_t WS_BUFA  = WS_SUMS  + 3072;
constexpr size_t WS_BUFB  = WS_BUFA  + 8388608;
constexpr size_t WS_NIDX1 = WS_BUFB  + 8388608;
constexpr size_t WS_NIDX2 = WS_NIDX1 + 262144;

// output offsets (float elements)
constexpr size_t OUT1 = 196608;   // pc_l1 [4][3][2048]
constexpr size_t OUT2 = 221184;   // pc_l2 [4][3][1024]
constexpr size_t OUT3 = 233472;   // feat_l2 [4][64][1024]
constexpr size_t OUT4 = 495616;   // fidx1 [4][2048] (float)
constexpr size_t OUT5 = 503808;   // fidx2 [4][1024] (float)

} // namespace

extern "C" void kernel_launch(void* const* d_in, const int* in_sizes, int n_in,
                              void* d_out, int out_size, void* d_ws, size_t ws_size,
                              hipStream_t stream)
{
  (void)in_sizes; (void)n_in; (void)out_size; (void)ws_size;
  const float* pc   = (const float*)d_in[0];
  const float* feat = (const float*)d_in[1];
  const float* W1 = (const float*)d_in[2];
  const float* W2 = (const float*)d_in[3];
  const float* W3 = (const float*)d_in[4];
  const float* W4 = (const float*)d_in[5];
  const float* W5 = (const float*)d_in[6];
  const float* W6 = (const float*)d_in[7];
  float* out = (float*)d_out;
  float* ws  = (float*)d_ws;

  float* xyz   = ws + WS_XYZ;
  float* fN    = ws + WS_FN;
  float* rsq0  = ws + WS_RSQ0;
  float* xyz1  = ws + WS_XYZ1;
  float* rsq1  = ws + WS_RSQ1;
  float* xyz2  = ws + WS_XYZ2;
  float* rsq2  = ws + WS_RSQ2;
  float* feat1 = ws + WS_FEAT1;
  float* sums  = ws + WS_SUMS;
  float* bufA  = ws + WS_BUFA;
  float* bufB  = ws + WS_BUFB;
  int* nidx1   = (int*)(ws + WS_NIDX1);
  int* nidx2   = (int*)(ws + WS_NIDX2);

  (void)hipMemsetAsync(sums, 0, 3072*sizeof(float), stream);

  k_setup<<<768, 256, 0, stream>>>(pc, feat, out, xyz, fN, rsq0);

  // ---- SA1 ----
  k_fps<N0, S1, 1024, 16><<<BB, 1024, 0, stream>>>(xyz, xyz1, rsq1, out+OUT1, out+OUT4);
  k_knn<N0, 32, S1><<<BB*S1, 512, 0, stream>>>(xyz1, rsq1, xyz, rsq0, nidx1);
  k_sa1_l1<<<1024, 256, 0, stream>>>(xyz, fN, xyz1, nidx1, W1, bufA, sums);
  k_sa_mid<32,32,16><<<1024, 256, 0, stream>>>(bufA, W2, sums,       bufB, sums+512,  262144, 1.0f/65536.0f);
  k_sa_mid<32,32,16><<<1024, 256, 0, stream>>>(bufB, W3, sums+512,   bufA, sums+1024, 262144, 1.0f/65536.0f);
  k_pool<32, 2048, 0><<<1024, 256, 0, stream>>>(bufA, sums+1024, feat1, 262144, 1.0f/65536.0f);

  // ---- SA2 ----
  k_fps<S1, S2, 512, 4><<<BB, 512, 0, stream>>>(xyz1, xyz2, rsq2, out+OUT2, out+OUT5);
  k_knn<S1, 4, S2><<<BB*S2, 512, 0, stream>>>(xyz2, rsq2, xyz1, rsq1, nidx2);
  k_sa2_l1<<<512, 256, 0, stream>>>(xyz1, feat1, xyz2, nidx2, W4, bufB, sums+1536);
  k_sa_mid<64,64,15><<<512, 256, 0, stream>>>(bufB, W5, sums+1536, bufA, sums+2048, 131072, 1.0f/32768.0f);
  k_sa_mid<64,64,15><<<512, 256, 0, stream>>>(bufA, W6, sums+2048, bufB, sums+2560, 131072, 1.0f/32768.0f);
  k_pool<64, 1024, 1><<<1024, 256, 0, stream>>>(bufB, sums+2560, out+OUT3, 131072, 1.0f/32768.0f);
}

// Round 15
// 6417.065 us; speedup vs baseline: 1.6927x; 1.6927x over previous
//
#include <hip/hip_runtime.h>
#include <math.h>

namespace {

constexpr int BB = 4;
constexpr int N0 = 16384;
constexpr int S1 = 2048;
constexpr int S2 = 1024;

// ---- exact f32 helpers (no contraction) ----
__device__ __forceinline__ float sq3(float x, float y, float z){
  #pragma clang fp contract(off)
  return x*x + y*y + z*z;
}
__device__ __forceinline__ float sqdist(float ax,float ay,float az,float bx,float by,float bz){
  #pragma clang fp contract(off)
  float dx = ax-bx; float dy = ay-by; float dz = az-bz;
  return dx*dx + dy*dy + dz*dz;
}
__device__ __forceinline__ float dot3(float ax,float ay,float az,float bx,float by,float bz){
  #pragma clang fp contract(off)
  return ax*bx + ay*by + az*bz;
}
__device__ __forceinline__ float knndist(float qs, float dot, float rs){
  #pragma clang fp contract(off)
  return (qs - 2.0f*dot) + rs;
}

// ---------------- setup: raw f32, point-major layout ----------------
__global__ __launch_bounds__(256) void k_setup(const float* __restrict__ pc,
                                               const float* __restrict__ feat,
                                               float* __restrict__ out_pc,
                                               float* __restrict__ xyz,
                                               float* __restrict__ fN,
                                               float* __restrict__ rsq0)
{
  int t = blockIdx.x*256 + threadIdx.x;
  if (t < BB*3*N0) out_pc[t] = pc[t];
  if (t < BB*N0){
    int b = t >> 14, n = t & (N0-1);
    const float* p = pc + (size_t)b*3*N0;
    float x = p[n], y = p[N0+n], z = p[2*N0+n];
    float* q = xyz + (size_t)t*3;
    q[0]=x; q[1]=y; q[2]=z;
    rsq0[t] = sq3(x,y,z);
    const float* f = feat + (size_t)b*3*N0;
    float* g = fN + (size_t)t*3;
    g[0]=f[n]; g[1]=f[N0+n]; g[2]=f[2*N0+n];
  }
}

// ---------------- FPS ----------------
// Reference semantics (verified r14): per-point Euclidean norm d = sqrt_rn(sum of
// squares), dist = min carried in sqrt domain, argmax with first-index ties.
// Equivalent fast form: carry dist in SQUARED domain (sqrt/min/max commute —
// monotone), reduce value-only max msq; s = sqrt(msq); lo = smallest f32 with
// sqrt_rn(lo)==s (preimage walk); winner = min global index with dist_sq >= lo.
__device__ __forceinline__ void fps_writeout(int b, int i, float cx, float cy, float cz, int far,
                                             float* sxyz, float* srsq, float* pcl, float* fidxf, int NP)
{
  fidxf[(size_t)b*NP + i] = (float)far;
  float* o = sxyz + ((size_t)b*NP + i)*3;
  o[0]=cx; o[1]=cy; o[2]=cz;
  float* pb = pcl + (size_t)b*3*NP;
  pb[i] = cx; pb[NP+i] = cy; pb[2*NP+i] = cz;
  srsq[(size_t)b*NP + i] = sq3(cx,cy,cz);
}

template<int N, int NP, int BS, int PPT>
__global__ __launch_bounds__(BS) void k_fps(const float* __restrict__ pts,   // [B][N][3]
                                            float* __restrict__ sxyz,        // [B][NP][3]
                                            float* __restrict__ srsq,        // [B][NP]
                                            float* __restrict__ pcl,         // [B][3][NP]
                                            float* __restrict__ fidxf)       // [B][NP] (float)
{
  static_assert(N == BS*PPT, "bad fps shape");
  int b = blockIdx.x, t = threadIdx.x;
  const float* P = pts + (size_t)b*N*3;
  float px[PPT], py[PPT], pz[PPT], dist[PPT];
  #pragma unroll
  for (int j=0;j<PPT;j++){
    int g = t + BS*j;
    px[j]=P[g*3]; py[j]=P[g*3+1]; pz[j]=P[g*3+2];
    dist[j]=1e10f;
  }
  __shared__ unsigned s_maxbits;
  __shared__ int      s_win;
  __shared__ float    s_lo;
  float cx = P[0], cy = P[1], cz = P[2];      // centroid carried in registers (uniform)
  if (t == 0){
    s_maxbits = 0u;
    s_win = 0x7FFFFFFF;
    fps_writeout(b, 0, cx, cy, cz, 0, sxyz, srsq, pcl, fidxf, NP);
  }
  __syncthreads();
  for (int i=1;i<NP;i++){
    // pass 1: update squared dists, track value-only max
    float vmax = -1.0f;
    #pragma unroll
    for (int j=0;j<PPT;j++){
      float d  = sqdist(px[j],py[j],pz[j],cx,cy,cz);
      float nd = fminf(dist[j], d);
      dist[j]  = nd;
      vmax = fmaxf(vmax, nd);
    }
    #pragma unroll
    for (int off=32; off>0; off>>=1) vmax = fmaxf(vmax, __shfl_down(vmax, off));
    if ((t & 63) == 0) atomicMax(&s_maxbits, __float_as_uint(vmax));  // bits-max == float-max for >=0
    __syncthreads();                                   // B1
    if (t == 0){
      unsigned mb = s_maxbits;
      float s = sqrtf(__uint_as_float(mb));
      unsigned xb = mb;
      while (xb > 0u && sqrtf(__uint_as_float(xb - 1u)) == s) xb--;   // sqrt-preimage lower edge (~2 steps)
      s_lo = __uint_as_float(xb);
      s_maxbits = 0u;
      s_win = 0x7FFFFFFF;   // reset here: ordered before next iter's atomicMin, after all reads of s_win
    }
    __syncthreads();                                   // B2
    float lo = s_lo;
    int li = 0x7FFFFFFF;
    #pragma unroll
    for (int j=PPT-1;j>=0;j--) if (dist[j] >= lo) li = t + BS*j;   // smallest j wins
    if (li != 0x7FFFFFFF) atomicMin(&s_win, li);       // only tie-set threads (1-3) hit this
    __syncthreads();                                   // B3
    int far = s_win;
    cx = P[(size_t)far*3]; cy = P[(size_t)far*3+1]; cz = P[(size_t)far*3+2];  // uniform broadcast load
    if (t == 0) fps_writeout(b, i, cx, cy, cz, far, sxyz, srsq, pcl, fidxf, NP);
  }
}

// ---------------- exact kNN (32 smallest) via radix select ----------------
template<int NREF, int PPT, int NQ>
__global__ __launch_bounds__(512) void k_knn(const float* __restrict__ qxyz,
                                             const float* __restrict__ qrsq,
                                             const float* __restrict__ rxyz,
                                             const float* __restrict__ rrsq,
                                             int* __restrict__ nidx)
{
  static_assert(NREF == 512*PPT, "bad knn shape");
  int q = blockIdx.x;
  int b = q / NQ;
  int t = threadIdx.x;
  const float* R  = rxyz + (size_t)b*NREF*3;
  const float* RS = rrsq + (size_t)b*NREF;
  float qx = qxyz[(size_t)q*3], qy = qxyz[(size_t)q*3+1], qz = qxyz[(size_t)q*3+2];
  float qs = qrsq[q];
  unsigned u[PPT];
  #pragma unroll
  for (int j=0;j<PPT;j++){
    int g = t + 512*j;
    float rx=R[g*3], ry=R[g*3+1], rz=R[g*3+2];
    float d = knndist(qs, dot3(qx,qy,qz,rx,ry,rz), RS[g]);
    unsigned bu = __float_as_uint(d);
    u[j] = ((int)bu < 0) ? ~bu : (bu | 0x80000000u);
  }
  __shared__ unsigned hist[256];
  __shared__ unsigned s_pref, s_pm, s_want, s_cnteq;
  __shared__ int s_n;
  __shared__ int s_eq[1024];
  __shared__ int s_ne;
  if (t == 0){ s_pref=0u; s_pm=0u; s_want=32u; s_n=0; s_ne=0; }

  for (int shift=24; shift>=0; shift-=8){
    if (t < 256) hist[t] = 0u;
    __syncthreads();
    unsigned pref = s_pref, pm = s_pm;
    #pragma unroll
    for (int j=0;j<PPT;j++){
      if ((u[j] & pm) == pref) atomicAdd(&hist[(u[j]>>shift)&255], 1u);
    }
    __syncthreads();
    if (t < 64){
      unsigned h0=hist[4*t], h1=hist[4*t+1], h2=hist[4*t+2], h3=hist[4*t+3];
      unsigned ssum = h0+h1+h2+h3;
      unsigned inc = ssum;
      #pragma unroll
      for (int off=1; off<64; off<<=1){
        unsigned o = __shfl_up(inc, off);
        if (t >= off) inc += o;
      }
      unsigned exc = inc - ssum;
      unsigned want = s_want;
      if (exc < want && want <= inc){
        unsigned rem = want - exc;
        unsigned bin, below;
        if      (rem <= h0)       { bin=4*t+0; below=exc; }
        else if (rem <= h0+h1)    { bin=4*t+1; below=exc+h0; }
        else if (rem <= h0+h1+h2) { bin=4*t+2; below=exc+h0+h1; }
        else                      { bin=4*t+3; below=exc+h0+h1+h2; }
        s_pref = pref | (bin << shift);
        s_pm   = pm   | (0xFFu << shift);
        s_want = want - below;
        if (shift == 0) s_cnteq = hist[bin];
      }
    }
    __syncthreads();
  }
  unsigned T = s_pref;
  unsigned krem = s_want;
  unsigned cnteq = s_cnteq;
  int* outq = nidx + (size_t)q*32;
  #pragma unroll
  for (int j=0;j<PPT;j++){
    if (u[j] < T){ int p = atomicAdd(&s_n, 1); outq[p] = t + 512*j; }
  }
  __syncthreads();
  if (cnteq == krem){
    #pragma unroll
    for (int j=0;j<PPT;j++){
      if (u[j] == T){ int p = atomicAdd(&s_n, 1); outq[p] = t + 512*j; }
    }
  } else {
    #pragma unroll
    for (int j=0;j<PPT;j++){
      if (u[j] == T){ int p = atomicAdd(&s_ne, 1); if (p < 1024) s_eq[p] = t + 512*j; }
    }
    __syncthreads();
    if (t == 0){
      int ne = s_ne; if (ne > 1024) ne = 1024;
      int p = s_n;
      int take = (int)krem; if (take > ne) take = ne;
      for (int r=0; r<take; r++){
        int mn = 0x7FFFFFFF, mi = -1;
        for (int e=0; e<ne; e++){ if (s_eq[e] < mn){ mn = s_eq[e]; mi = e; } }
        if (mi < 0) break;
        outq[p++] = mn;
        s_eq[mi] = 0x7FFFFFFF;
      }
    }
  }
}

// ---------------- per-layer sum/sumsq accumulation ----------------
template<int C>
__device__ __forceinline__ void accum_sums(const float* o, int b, float* sums){
  __shared__ float s_sum[C];
  __shared__ float s_ssq[C];
  int t = threadIdx.x;
  if (t < C){ s_sum[t]=0.f; s_ssq[t]=0.f; }
  __syncthreads();
  int lane = t & 63;
  #pragma unroll
  for (int c=0;c<C;c++){
    float v = o[c], v2 = v*v;
    #pragma unroll
    for (int off=32; off>0; off>>=1){ v += __shfl_down(v, off); v2 += __shfl_down(v2, off); }
    if (lane == 0){ atomicAdd(&s_sum[c], v); atomicAdd(&s_ssq[c], v2); }
  }
  __syncthreads();
  if (t < C){
    atomicAdd(&sums[(b*64+t)*2],   s_sum[t]);
    atomicAdd(&sums[(b*64+t)*2+1], s_ssq[t]);
  }
}

// ---------------- SA1 layer 1 ----------------
__global__ __launch_bounds__(256) void k_sa1_l1(const float* __restrict__ xyz,
                                                const float* __restrict__ fN,
                                                const float* __restrict__ sxyz,
                                                const int* __restrict__ nidx,
                                                const float* __restrict__ W,
                                                float* __restrict__ xout,
                                                float* __restrict__ sums)
{
  __shared__ float sW[192];
  int t = threadIdx.x;
  if (t < 192) sW[t] = W[t];
  int row = blockIdx.x*256 + t;
  int b = row >> 16;
  int sk = row & 65535;
  int s = sk >> 5;
  int nb = nidx[row];
  const float* pr = xyz  + ((size_t)(b*N0 + nb))*3;
  const float* pq = sxyz + ((size_t)(b*S1 + s ))*3;
  const float* pf = fN   + ((size_t)(b*N0 + nb))*3;
  float i0 = pr[0]-pq[0], i1 = pr[1]-pq[1], i2 = pr[2]-pq[2];
  float i3 = pf[0], i4 = pf[1], i5 = pf[2];
  __syncthreads();
  float o[32];
  #pragma unroll
  for (int c=0;c<32;c++){
    float a = i0*sW[c];
    a = fmaf(i1, sW[ 32+c], a);
    a = fmaf(i2, sW[ 64+c], a);
    a = fmaf(i3, sW[ 96+c], a);
    a = fmaf(i4, sW[128+c], a);
    a = fmaf(i5, sW[160+c], a);
    o[c] = a;
    xout[(size_t)c*262144 + row] = a;
  }
  accum_sums<32>(o, b, sums);
}

// ---------------- mid layer ----------------
template<int CIN, int COUT, int LRPB>
__global__ __launch_bounds__(256) void k_sa_mid(const float* __restrict__ xin,
                                                const float* __restrict__ W,
                                                const float* __restrict__ sums_in,
                                                float* __restrict__ xout,
                                                float* __restrict__ sums_out,
                                                int rows_total, float invM)
{
  __shared__ float sW[CIN*COUT];
  __shared__ float s_mu[CIN];
  __shared__ float s_rs[CIN];
  int t = threadIdx.x;
  int row = blockIdx.x*256 + t;
  int bb = (blockIdx.x*256) >> LRPB;
  for (int i=t; i<CIN*COUT; i+=256) sW[i] = W[i];
  if (t < CIN){
    float sm = sums_in[(bb*64+t)*2], sq = sums_in[(bb*64+t)*2+1];
    float mu = sm*invM;
    float var = fmaxf(sq*invM - mu*mu, 0.f);
    s_mu[t] = mu;
    s_rs[t] = 1.0f/sqrtf(var + 1e-5f);
  }
  __syncthreads();
  float o[COUT];
  #pragma unroll
  for (int d=0;d<COUT;d++) o[d] = 0.f;
  #pragma unroll
  for (int c=0;c<CIN;c++){
    float x = xin[(size_t)c*rows_total + row];
    float v = fmaxf((x - s_mu[c])*s_rs[c], 0.f);
    #pragma unroll
    for (int d=0;d<COUT;d++) o[d] = fmaf(v, sW[c*COUT+d], o[d]);
  }
  #pragma unroll
  for (int d=0;d<COUT;d++) xout[(size_t)d*rows_total + row] = o[d];
  accum_sums<COUT>(o, bb, sums_out);
}

// ---------------- SA2 layer 1 ----------------
__global__ __launch_bounds__(256) void k_sa2_l1(const float* __restrict__ xyz1,
                                                const float* __restrict__ feat1,
                                                const float* __restrict__ xyz2,
                                                const int* __restrict__ nidx,
                                                const float* __restrict__ W,
                                                float* __restrict__ xout,
                                                float* __restrict__ sums)
{
  __shared__ float sW[35*64];
  int t = threadIdx.x;
  for (int i=t; i<35*64; i+=256) sW[i] = W[i];
  int row = blockIdx.x*256 + t;
  int b = row >> 15;
  int sk = row & 32767;
  int s = sk >> 5;
  int nb = nidx[row];
  const float* pr = xyz1 + ((size_t)(b*S1 + nb))*3;
  const float* pq = xyz2 + ((size_t)(b*S2 + s ))*3;
  const float* pf = feat1 + ((size_t)(b*S1 + nb))*32;
  float i0 = pr[0]-pq[0], i1 = pr[1]-pq[1], i2 = pr[2]-pq[2];
  float fv[32];
  #pragma unroll
  for (int c=0;c<32;c++) fv[c] = pf[c];
  __syncthreads();
  float o[64];
  #pragma unroll
  for (int d=0;d<64;d++){
    float a = i0*sW[d];
    a = fmaf(i1, sW[ 64+d], a);
    a = fmaf(i2, sW[128+d], a);
    o[d] = a;
  }
  #pragma unroll
  for (int c=0;c<32;c++){
    float v = fv[c];
    #pragma unroll
    for (int d=0;d<64;d++) o[d] = fmaf(v, sW[(3+c)*64+d], o[d]);
  }
  #pragma unroll
  for (int d=0;d<64;d++) xout[(size_t)d*131072 + row] = o[d];
  accum_sums<64>(o, b, sums);
}

// ---------------- final norm+relu+maxpool ----------------
template<int C, int PTSB, int CF>
__global__ __launch_bounds__(256) void k_pool(const float* __restrict__ xin,
                                              const float* __restrict__ sums_in,
                                              float* __restrict__ out,
                                              int rows_total, float invM)
{
  int t = threadIdx.x;
  int c = t & (C-1);
  int pl = t / C;
  int p = blockIdx.x*(256/C) + pl;
  int b = p / PTSB;
  float sm = sums_in[(b*64+c)*2], sq = sums_in[(b*64+c)*2+1];
  float mu = sm*invM;
  float var = fmaxf(sq*invM - mu*mu, 0.f);
  float rs = 1.0f/sqrtf(var + 1e-5f);
  const float* xp = xin + (size_t)c*rows_total + (size_t)p*32;
  float m = -1e30f;
  #pragma unroll
  for (int k=0;k<32;k++) m = fmaxf(m, xp[k]);
  m = fmaxf((m - mu)*rs, 0.0f);
  if (CF) out[((size_t)(b*C + c))*PTSB + (p - b*PTSB)] = m;
  else    out[(size_t)p*C + c] = m;
}

// ---------------- workspace layout (float element offsets) ----------------
constexpr size_t WS_XYZ   = 0;
constexpr size_t WS_FN    = WS_XYZ   + 196608;
constexpr size_t WS_RSQ0  = WS_FN    + 196608;
constexpr size_t WS_XYZ1  = WS_RSQ0  + 65536;
constexpr size_t WS_RSQ1  = WS_XYZ1  + 24576;
constexpr size_t WS_XYZ2  = WS_RSQ1  + 8192;
constexpr size_t WS_RSQ2  = WS_XYZ2  + 12288;
constexpr size_t WS_FEAT1 = WS_RSQ2  + 4096;
constexpr size_t WS_SUMS  = WS_FEAT1 + 262144;
constexpr size_t WS_BUFA  = WS_SUMS  + 3072;
constexpr size_t WS_BUFB  = WS_BUFA  + 8388608;
constexpr size_t WS_NIDX1 = WS_BUFB  + 8388608;
constexpr size_t WS_NIDX2 = WS_NIDX1 + 262144;

// output offsets (float elements)
constexpr size_t OUT1 = 196608;   // pc_l1 [4][3][2048]
constexpr size_t OUT2 = 221184;   // pc_l2 [4][3][1024]
constexpr size_t OUT3 = 233472;   // feat_l2 [4][64][1024]
constexpr size_t OUT4 = 495616;   // fidx1 [4][2048] (float)
constexpr size_t OUT5 = 503808;   // fidx2 [4][1024] (float)

} // namespace

extern "C" void kernel_launch(void* const* d_in, const int* in_sizes, int n_in,
                              void* d_out, int out_size, void* d_ws, size_t ws_size,
                              hipStream_t stream)
{
  (void)in_sizes; (void)n_in; (void)out_size; (void)ws_size;
  const float* pc   = (const float*)d_in[0];
  const float* feat = (const float*)d_in[1];
  const float* W1 = (const float*)d_in[2];
  const float* W2 = (const float*)d_in[3];
  const float* W3 = (const float*)d_in[4];
  const float* W4 = (const float*)d_in[5];
  const float* W5 = (const float*)d_in[6];
  const float* W6 = (const float*)d_in[7];
  float* out = (float*)d_out;
  float* ws  = (float*)d_ws;

  float* xyz   = ws + WS_XYZ;
  float* fN    = ws + WS_FN;
  float* rsq0  = ws + WS_RSQ0;
  float* xyz1  = ws + WS_XYZ1;
  float* rsq1  = ws + WS_RSQ1;
  float* xyz2  = ws + WS_XYZ2;
  float* rsq2  = ws + WS_RSQ2;
  float* feat1 = ws + WS_FEAT1;
  float* sums  = ws + WS_SUMS;
  float* bufA  = ws + WS_BUFA;
  float* bufB  = ws + WS_BUFB;
  int* nidx1   = (int*)(ws + WS_NIDX1);
  int* nidx2   = (int*)(ws + WS_NIDX2);

  (void)hipMemsetAsync(sums, 0, 3072*sizeof(float), stream);

  k_setup<<<768, 256, 0, stream>>>(pc, feat, out, xyz, fN, rsq0);

  // ---- SA1 ----
  k_fps<N0, S1, 1024, 16><<<BB, 1024, 0, stream>>>(xyz, xyz1, rsq1, out+OUT1, out+OUT4);
  k_knn<N0, 32, S1><<<BB*S1, 512, 0, stream>>>(xyz1, rsq1, xyz, rsq0, nidx1);
  k_sa1_l1<<<1024, 256, 0, stream>>>(xyz, fN, xyz1, nidx1, W1, bufA, sums);
  k_sa_mid<32,32,16><<<1024, 256, 0, stream>>>(bufA, W2, sums,       bufB, sums+512,  262144, 1.0f/65536.0f);
  k_sa_mid<32,32,16><<<1024, 256, 0, stream>>>(bufB, W3, sums+512,   bufA, sums+1024, 262144, 1.0f/65536.0f);
  k_pool<32, 2048, 0><<<1024, 256, 0, stream>>>(bufA, sums+1024, feat1, 262144, 1.0f/65536.0f);

  // ---- SA2 ----
  k_fps<S1, S2, 256, 8><<<BB, 256, 0, stream>>>(xyz1, xyz2, rsq2, out+OUT2, out+OUT5);
  k_knn<S1, 4, S2><<<BB*S2, 512, 0, stream>>>(xyz2, rsq2, xyz1, rsq1, nidx2);
  k_sa2_l1<<<512, 256, 0, stream>>>(xyz1, feat1, xyz2, nidx2, W4, bufB, sums+1536);
  k_sa_mid<64,64,15><<<512, 256, 0, stream>>>(bufB, W5, sums+1536, bufA, sums+2048, 131072, 1.0f/32768.0f);
  k_sa_mid<64,64,15><<<512, 256, 0, stream>>>(bufA, W6, sums+2048, bufB, sums+2560, 131072, 1.0f/32768.0f);
  k_pool<64, 1024, 1><<<1024, 256, 0, stream>>>(bufB, sums+2560, out+OUT3, 131072, 1.0f/32768.0f);
}